// Round 1
// baseline (114.135 us; speedup 1.0000x reference)
//
#include <hip/hip_runtime.h>

#define B_ 8
#define N_ 64
#define T_ 512
#define D_ 128
#define H_ 7

// LDS row stride for the 64x128 f32 tile: 132 words (33 float4 units, odd)
// -> stage-write, row-read (logits), chunk-read (ctx) are all conflict-free.
#define SROW 132

__global__ __launch_bounds__(256, 4)
void MultiHeadPool_45226005627089_kernel(const float* __restrict__ others,
                                         const float* __restrict__ queries,
                                         float* __restrict__ out) {
    __shared__ __align__(16) float S[N_ * SROW];   // 33792 B (reused for ctx partials)
    __shared__ __align__(16) float LG[H_ * 68];    // logits, stride 68
    __shared__ __align__(16) float WS[H_ * 68];    // softmax weights, stride 68

    const int tid = threadIdx.x;
    const int bt  = blockIdx.x;          // = b*T_ + t
    const int b   = bt >> 9;             // /T_
    const int t   = bt & (T_ - 1);

    const float* obase = others + ((size_t)b * N_ * T_ + (size_t)t) * D_; // + n*T_*D_ + d

    // ---- stage S: (u,g) mapping, 512B-contiguous per half-wave ----
    {
        const int u = tid & 31;
        const int g = tid >> 5;
        #pragma unroll
        for (int k = 0; k < 8; ++k) {
            const int n = g * 8 + k;
            float4 v = *reinterpret_cast<const float4*>(obase + (size_t)n * (T_ * D_) + u * 4);
            *reinterpret_cast<float4*>(&S[n * SROW + u * 4]) = v;
        }
    }
    __syncthreads();

    // ---- logits: thread (n2, c) dots 32-float chunk against q (q from global/L1) ----
    {
        const int n2 = tid >> 2;
        const int c  = tid & 3;
        float4 s4[8];
        #pragma unroll
        for (int dd = 0; dd < 8; ++dd)
            s4[dd] = *reinterpret_cast<const float4*>(&S[n2 * SROW + c * 32 + dd * 4]);

        float part[H_];
        #pragma unroll
        for (int h = 0; h < H_; ++h) {
            float acc = 0.f;
            #pragma unroll
            for (int dd = 0; dd < 8; ++dd) {
                float4 qv = *reinterpret_cast<const float4*>(queries + h * D_ + c * 32 + dd * 4);
                acc = fmaf(s4[dd].x, qv.x, acc);
                acc = fmaf(s4[dd].y, qv.y, acc);
                acc = fmaf(s4[dd].z, qv.z, acc);
                acc = fmaf(s4[dd].w, qv.w, acc);
            }
            part[h] = acc;
        }
        #pragma unroll
        for (int h = 0; h < H_; ++h) {
            part[h] += __shfl_xor(part[h], 1);
            part[h] += __shfl_xor(part[h], 2);
        }
        if (c == 0) {
            const float scale = 0.0883883476483184f;  // 128^-0.5
            #pragma unroll
            for (int h = 0; h < H_; ++h)
                LG[h * 68 + n2] = part[h] * scale;
        }
    }
    __syncthreads();

    // ---- softmax over n (one wave per h, two rounds) ----
    {
        const int wv   = tid >> 6;
        const int lane = tid & 63;
        #pragma unroll
        for (int rep = 0; rep < 2; ++rep) {
            const int h = wv + rep * 4;
            if (h < H_) {
                const float x = LG[h * 68 + lane];
                float m = x;
                #pragma unroll
                for (int k = 32; k >= 1; k >>= 1)
                    m = fmaxf(m, __shfl_xor(m, k));
                const float e = __expf(x - m);
                float s = e;
                #pragma unroll
                for (int k = 32; k >= 1; k >>= 1)
                    s += __shfl_xor(s, k);
                WS[h * 68 + lane] = e / s;
            }
        }
    }
    __syncthreads();

    // ---- ctx: thread (u,g) reads S once, accumulates all 7 heads over its 8 rows ----
    const int u = tid & 31;
    const int g = tid >> 5;
    float4 acc[H_];
    {
        float4 sreg[8];
        #pragma unroll
        for (int k = 0; k < 8; ++k)
            sreg[k] = *reinterpret_cast<const float4*>(&S[(g * 8 + k) * SROW + u * 4]);

        #pragma unroll
        for (int h = 0; h < H_; ++h) {
            const float4 w0 = *reinterpret_cast<const float4*>(&WS[h * 68 + g * 8]);
            const float4 w1 = *reinterpret_cast<const float4*>(&WS[h * 68 + g * 8 + 4]);
            float4 a; a.x = a.y = a.z = a.w = 0.f;
#define ACC4(wc, sr) \
            a.x = fmaf((wc), (sr).x, a.x); a.y = fmaf((wc), (sr).y, a.y); \
            a.z = fmaf((wc), (sr).z, a.z); a.w = fmaf((wc), (sr).w, a.w);
            ACC4(w0.x, sreg[0]) ACC4(w0.y, sreg[1]) ACC4(w0.z, sreg[2]) ACC4(w0.w, sreg[3])
            ACC4(w1.x, sreg[4]) ACC4(w1.y, sreg[5]) ACC4(w1.z, sreg[6]) ACC4(w1.w, sreg[7])
#undef ACC4
            acc[h] = a;
        }
    }
    __syncthreads();   // all S reads done -> safe to reuse S as partial buffer

    float4* part4 = reinterpret_cast<float4*>(S);  // [g][h][u] : 8*7*32 float4 = 28 KB
    #pragma unroll
    for (int h = 0; h < H_; ++h)
        part4[g * (H_ * 32) + h * 32 + u] = acc[h];
    __syncthreads();

    // ---- 8-way reduce + coalesced store ----
    if (tid < H_ * 32) {
        const int h  = tid >> 5;
        const int uu = tid & 31;
        float4 sum; sum.x = sum.y = sum.z = sum.w = 0.f;
        #pragma unroll
        for (int gg = 0; gg < 8; ++gg) {
            const float4 p = part4[gg * (H_ * 32) + h * 32 + uu];
            sum.x += p.x; sum.y += p.y; sum.z += p.z; sum.w += p.w;
        }
        *reinterpret_cast<float4*>(out + ((size_t)bt * H_ + h) * D_ + uu * 4) = sum;
    }
}

extern "C" void kernel_launch(void* const* d_in, const int* in_sizes, int n_in,
                              void* d_out, int out_size, void* d_ws, size_t ws_size,
                              hipStream_t stream) {
    // d_in[0] = ego (B,T,D)  -- unused by the reference computation
    const float* others  = (const float*)d_in[1];   // (B,N,T,D) f32
    const float* queries = (const float*)d_in[2];   // (H,D) f32
    float* out = (float*)d_out;                     // (B,T,H,D) f32

    dim3 grid(B_ * T_);
    dim3 block(256);
    MultiHeadPool_45226005627089_kernel<<<grid, block, 0, stream>>>(others, queries, out);
}

// Round 2
// 68.149 us; speedup vs baseline: 1.6748x; 1.6748x over previous
//
#include <hip/hip_runtime.h>

#define B_ 8
#define N_ 64
#define T_ 512
#define D_ 128
#define H_ 7
#define TPB 4      // t-values per block; grid = B*T/TPB = 1024 = 4 blocks/CU (all resident)
#define SROW 132   // LDS row stride for the 64x128 f32 tile
#define QROW 228   // per-c stride for staged queries (7*32 + 4 pad -> c's land on disjoint banks)

__global__ __launch_bounds__(256, 4)
void MultiHeadPool_45226005627089_kernel(const float* __restrict__ others,
                                         const float* __restrict__ queries,
                                         float* __restrict__ out) {
    __shared__ __align__(16) float S[N_ * SROW];   // 33792 B (aliased by ctx partials)
    __shared__ __align__(16) float qL[4 * QROW];   // 3648 B staged queries
    __shared__ __align__(16) float LG[H_ * 68];    // logits
    __shared__ __align__(16) float WS[H_ * 68];    // softmax weights

    const int tid = threadIdx.x;
    const int blk = blockIdx.x;
    const int b   = blk >> 7;              // 128 blocks per batch
    const int t0  = (blk & 127) * TPB;

    const int u = tid & 31;
    const int g = tid >> 5;

    const float* obase = others + (size_t)b * (N_ * T_ * D_);

    // ---- stage queries to LDS once (keeps compute phases free of vmem ops) ----
    if (tid < 224) {
        const int c  = tid / 56;
        const int r  = tid % 56;
        const int h  = r >> 3;
        const int dd = r & 7;
        *reinterpret_cast<float4*>(&qL[c * QROW + h * 32 + dd * 4]) =
            *reinterpret_cast<const float4*>(queries + h * D_ + c * 32 + dd * 4);
    }

    // ---- prefetch first t into registers ----
    float4 pre[8];
    #pragma unroll
    for (int k = 0; k < 8; ++k)
        pre[k] = *reinterpret_cast<const float4*>(
            obase + ((size_t)(g * 8 + k) * T_ + t0) * D_ + u * 4);

    for (int i = 0; i < TPB; ++i) {
        const int t = t0 + i;

        // regs -> LDS (waits only on our own prefetch)
        #pragma unroll
        for (int k = 0; k < 8; ++k)
            *reinterpret_cast<float4*>(&S[(g * 8 + k) * SROW + u * 4]) = pre[k];

        // fire-and-forget prefetch of next t; lands during the compute phases below
        if (i + 1 < TPB) {
            #pragma unroll
            for (int k = 0; k < 8; ++k)
                pre[k] = *reinterpret_cast<const float4*>(
                    obase + ((size_t)(g * 8 + k) * T_ + (t + 1)) * D_ + u * 4);
        }
        __syncthreads();

        // ---- logits: thread (n2, c) dots a 32-float chunk; q from LDS ----
        {
            const int n2 = tid >> 2;
            const int c  = tid & 3;
            const float* qc = &qL[c * QROW];
            float4 s4[8];
            #pragma unroll
            for (int dd = 0; dd < 8; ++dd)
                s4[dd] = *reinterpret_cast<const float4*>(&S[n2 * SROW + c * 32 + dd * 4]);

            float part[H_];
            #pragma unroll
            for (int h = 0; h < H_; ++h) {
                float acc = 0.f;
                #pragma unroll
                for (int dd = 0; dd < 8; ++dd) {
                    const float4 qv = *reinterpret_cast<const float4*>(qc + h * 32 + dd * 4);
                    acc = fmaf(s4[dd].x, qv.x, acc);
                    acc = fmaf(s4[dd].y, qv.y, acc);
                    acc = fmaf(s4[dd].z, qv.z, acc);
                    acc = fmaf(s4[dd].w, qv.w, acc);
                }
                part[h] = acc;
            }
            #pragma unroll
            for (int h = 0; h < H_; ++h) {
                part[h] += __shfl_xor(part[h], 1);
                part[h] += __shfl_xor(part[h], 2);
            }
            if (c == 0) {
                const float scale = 0.0883883476483184f;  // 128^-0.5
                #pragma unroll
                for (int h = 0; h < H_; ++h)
                    LG[h * 68 + n2] = part[h] * scale;
            }
        }
        __syncthreads();

        // ---- softmax over n (one wave per h, two rounds) ----
        {
            const int wv   = tid >> 6;
            const int lane = tid & 63;
            #pragma unroll
            for (int rep = 0; rep < 2; ++rep) {
                const int h = wv + rep * 4;
                if (h < H_) {
                    const float x = LG[h * 68 + lane];
                    float m = x;
                    #pragma unroll
                    for (int k = 32; k >= 1; k >>= 1)
                        m = fmaxf(m, __shfl_xor(m, k));
                    const float e = __expf(x - m);
                    float s = e;
                    #pragma unroll
                    for (int k = 32; k >= 1; k >>= 1)
                        s += __shfl_xor(s, k);
                    WS[h * 68 + lane] = e / s;
                }
            }
        }
        __syncthreads();

        // ---- ctx: (u,g) accumulates 7 heads over its 8 rows, in two half-passes ----
        float4 acc[H_];
        #pragma unroll
        for (int h = 0; h < H_; ++h) { acc[h].x = acc[h].y = acc[h].z = acc[h].w = 0.f; }
        #pragma unroll
        for (int half = 0; half < 2; ++half) {
            float4 sreg[4];
            #pragma unroll
            for (int k = 0; k < 4; ++k)
                sreg[k] = *reinterpret_cast<const float4*>(
                    &S[(g * 8 + half * 4 + k) * SROW + u * 4]);
            #pragma unroll
            for (int h = 0; h < H_; ++h) {
                const float4 w4 = *reinterpret_cast<const float4*>(
                    &WS[h * 68 + g * 8 + half * 4]);
#define ACC4(wc, sr) \
                acc[h].x = fmaf((wc), (sr).x, acc[h].x); acc[h].y = fmaf((wc), (sr).y, acc[h].y); \
                acc[h].z = fmaf((wc), (sr).z, acc[h].z); acc[h].w = fmaf((wc), (sr).w, acc[h].w);
                ACC4(w4.x, sreg[0]) ACC4(w4.y, sreg[1]) ACC4(w4.z, sreg[2]) ACC4(w4.w, sreg[3])
#undef ACC4
            }
        }
        __syncthreads();   // all S reads done -> safe to alias S with partials

        float4* part4 = reinterpret_cast<float4*>(S);  // [g][h][u] : 8*7*32 float4 = 28 KB
        #pragma unroll
        for (int h = 0; h < H_; ++h)
            part4[g * (H_ * 32) + h * 32 + u] = acc[h];
        __syncthreads();

        // ---- 8-way reduce + coalesced store ----
        if (tid < H_ * 32) {
            const int h = tid >> 5;
            float4 sum; sum.x = sum.y = sum.z = sum.w = 0.f;
            #pragma unroll
            for (int gg = 0; gg < 8; ++gg) {
                const float4 p = part4[gg * (H_ * 32) + h * 32 + u];
                sum.x += p.x; sum.y += p.y; sum.z += p.z; sum.w += p.w;
            }
            *reinterpret_cast<float4*>(
                out + (((size_t)(b * T_ + t)) * H_ + h) * D_ + u * 4) = sum;
        }
        __syncthreads();   // partials (aliasing S) fully read before next t's stage
    }
}

extern "C" void kernel_launch(void* const* d_in, const int* in_sizes, int n_in,
                              void* d_out, int out_size, void* d_ws, size_t ws_size,
                              hipStream_t stream) {
    // d_in[0] = ego (B,T,D) -- unused by the reference computation
    const float* others  = (const float*)d_in[1];   // (B,N,T,D) f32
    const float* queries = (const float*)d_in[2];   // (H,D) f32
    float* out = (float*)d_out;                     // (B,T,H,D) f32

    dim3 grid(B_ * T_ / TPB);
    dim3 block(256);
    MultiHeadPool_45226005627089_kernel<<<grid, block, 0, stream>>>(others, queries, out);
}

// Round 3
// 42.107 us; speedup vs baseline: 2.7106x; 1.6185x over previous
//
#include <hip/hip_runtime.h>

#define B_ 8
#define N_ 64
#define T_ 512
#define D_ 128
#define H_ 7
#define QROW 228   // per-c stride for staged queries (7*32 + 4 pad)

__global__ __launch_bounds__(256, 6)
void MultiHeadPool_45226005627089_kernel(const float* __restrict__ others,
                                         const float* __restrict__ queries,
                                         float* __restrict__ out) {
    __shared__ __align__(16) float qL[4 * QROW];        // 3648 B staged queries
    __shared__ float LG[H_ * 68];                       // logits
    __shared__ float WS[H_ * 68];                       // softmax weights
    __shared__ __align__(16) float P[4 * H_ * 32 * 4];  // wave partials, 14336 B

    const int tid = threadIdx.x;
    const int bt  = blockIdx.x;           // = b*T + t
    const int b   = bt >> 9;
    const int t   = bt & (T_ - 1);

    const float* obase = others + ((size_t)b * N_ * T_ + (size_t)t) * D_; // + n*T_*D_ + d

    // ---- stage queries to LDS (tiny, L1-hot) ----
    if (tid < 224) {
        const int c  = tid / 56;
        const int r  = tid % 56;
        const int h  = r >> 3;
        const int dd = r & 7;
        *reinterpret_cast<float4*>(&qL[c * QROW + h * 32 + dd * 4]) =
            *reinterpret_cast<const float4*>(queries + h * D_ + c * 32 + dd * 4);
    }
    __syncthreads();

    // ---- phase 1: logits. thread (n2,c) reads its contiguous 128B chunk from GLOBAL ----
    {
        const int n2 = tid >> 2;
        const int c  = tid & 3;
        const float* rbase = obase + (size_t)n2 * (T_ * D_) + c * 32;
        float4 s4[8];
        #pragma unroll
        for (int dd = 0; dd < 8; ++dd)
            s4[dd] = *reinterpret_cast<const float4*>(rbase + dd * 4);

        const float* qc = &qL[c * QROW];
        float part[H_];
        #pragma unroll
        for (int h = 0; h < H_; ++h) {
            float acc = 0.f;
            #pragma unroll
            for (int dd = 0; dd < 8; ++dd) {
                const float4 qv = *reinterpret_cast<const float4*>(qc + h * 32 + dd * 4);
                acc = fmaf(s4[dd].x, qv.x, acc);
                acc = fmaf(s4[dd].y, qv.y, acc);
                acc = fmaf(s4[dd].z, qv.z, acc);
                acc = fmaf(s4[dd].w, qv.w, acc);
            }
            part[h] = acc;
        }
        #pragma unroll
        for (int h = 0; h < H_; ++h) {
            part[h] += __shfl_xor(part[h], 1);
            part[h] += __shfl_xor(part[h], 2);
        }
        if (c == 0) {
            const float scale = 0.0883883476483184f;  // 128^-0.5
            #pragma unroll
            for (int h = 0; h < H_; ++h)
                LG[h * 68 + n2] = part[h] * scale;
        }
    }
    __syncthreads();

    // ---- softmax over n (one wave per h, two rounds) ----
    {
        const int wv   = tid >> 6;
        const int lane = tid & 63;
        #pragma unroll
        for (int rep = 0; rep < 2; ++rep) {
            const int h = wv + rep * 4;
            if (h < H_) {
                const float x = LG[h * 68 + lane];
                float m = x;
                #pragma unroll
                for (int k = 32; k >= 1; k >>= 1)
                    m = fmaxf(m, __shfl_xor(m, k));
                const float e = __expf(x - m);
                float s = e;
                #pragma unroll
                for (int k = 32; k >= 1; k >>= 1)
                    s += __shfl_xor(s, k);
                WS[h * 68 + lane] = e / s;
            }
        }
    }
    __syncthreads();

    // ---- phase 2: ctx. thread (u,g) re-reads its 8 rows from GLOBAL (L1/L2-hot) ----
    {
        const int u = tid & 31;
        const int g = tid >> 5;
        float4 acc[H_];
        #pragma unroll
        for (int h = 0; h < H_; ++h) { acc[h].x = acc[h].y = acc[h].z = acc[h].w = 0.f; }

        #pragma unroll
        for (int k = 0; k < 8; ++k) {
            const int row = g * 8 + k;
            const float4 v = *reinterpret_cast<const float4*>(
                obase + (size_t)row * (T_ * D_) + u * 4);
            #pragma unroll
            for (int h = 0; h < H_; ++h) {
                const float w = WS[h * 68 + row];
                acc[h].x = fmaf(w, v.x, acc[h].x);
                acc[h].y = fmaf(w, v.y, acc[h].y);
                acc[h].z = fmaf(w, v.z, acc[h].z);
                acc[h].w = fmaf(w, v.w, acc[h].w);
            }
        }

        // fold the wave's two g-groups (lane u <-> lane u+32)
        #pragma unroll
        for (int h = 0; h < H_; ++h) {
            acc[h].x += __shfl_xor(acc[h].x, 32);
            acc[h].y += __shfl_xor(acc[h].y, 32);
            acc[h].z += __shfl_xor(acc[h].z, 32);
            acc[h].w += __shfl_xor(acc[h].w, 32);
        }

        const int wv = tid >> 6;
        float4* P4 = reinterpret_cast<float4*>(P);
        if ((tid & 63) < 32) {
            #pragma unroll
            for (int h = 0; h < H_; ++h)
                P4[(wv * H_ + h) * 32 + u] = acc[h];
        }
    }
    __syncthreads();

    // ---- final 4-way reduce + coalesced store ----
    if (tid < H_ * 32) {
        const int h = tid >> 5;
        const int u = tid & 31;
        const float4* P4 = reinterpret_cast<const float4*>(P);
        float4 sum; sum.x = sum.y = sum.z = sum.w = 0.f;
        #pragma unroll
        for (int wv = 0; wv < 4; ++wv) {
            const float4 p = P4[(wv * H_ + h) * 32 + u];
            sum.x += p.x; sum.y += p.y; sum.z += p.z; sum.w += p.w;
        }
        *reinterpret_cast<float4*>(out + ((size_t)bt * H_ + h) * D_ + u * 4) = sum;
    }
}

extern "C" void kernel_launch(void* const* d_in, const int* in_sizes, int n_in,
                              void* d_out, int out_size, void* d_ws, size_t ws_size,
                              hipStream_t stream) {
    // d_in[0] = ego (B,T,D) -- unused by the reference computation
    const float* others  = (const float*)d_in[1];   // (B,N,T,D) f32
    const float* queries = (const float*)d_in[2];   // (H,D) f32
    float* out = (float*)d_out;                     // (B,T,H,D) f32

    dim3 grid(B_ * T_);
    dim3 block(256);
    MultiHeadPool_45226005627089_kernel<<<grid, block, 0, stream>>>(others, queries, out);
}

// Round 4
// 37.960 us; speedup vs baseline: 3.0067x; 1.1093x over previous
//
#include <hip/hip_runtime.h>

#define B_ 8
#define N_ 64
#define T_ 512
#define D_ 128
#define H_ 7

// Single-pass: each thread (u = d-chunk, g = row-group) loads its 8 rows x float4
// ONCE; logits via in-wave reduce-scatter butterfly; ctx from the same registers.
__global__ __launch_bounds__(256, 5)
void MultiHeadPool_45226005627089_kernel(const float* __restrict__ others,
                                         const float* __restrict__ queries,
                                         float* __restrict__ out) {
    __shared__ __align__(16) float4 qL4[H_ * 32];     // 3584 B staged queries
    __shared__ float LG[H_ * 68];                     // logits (stride 68)
    __shared__ float WS[H_ * 68];                     // softmax weights
    __shared__ __align__(16) float4 P4[4 * H_ * 32];  // per-wave ctx partials, 14336 B

    const int tid = threadIdx.x;
    const int bt  = blockIdx.x;          // = b*T + t
    const int b   = bt >> 9;
    const int t   = bt & (T_ - 1);
    const int u   = tid & 31;
    const int g   = tid >> 5;

    const float* obase = others + ((size_t)b * N_ * T_ + (size_t)t) * D_; // + n*T*D + d

    // stage queries (qL4[h*32+u] = 16B chunk u of head h)
    if (tid < H_ * 32)
        qL4[tid] = reinterpret_cast<const float4*>(queries)[tid];

    // the ONLY global read of `others`: 8 rows x 16B per thread, 512B/half-wave
    float4 v[8];
    #pragma unroll
    for (int k = 0; k < 8; ++k)
        v[k] = *reinterpret_cast<const float4*>(
            obase + (size_t)(g * 8 + k) * (T_ * D_) + u * 4);

    __syncthreads();   // qL4 ready

    // ---- logits: two batches of 4 rows; reduce-scatter over the 32 u-lanes ----
    // after 5 halving steps lane u holds value j = bitrev5(u); j = kl*8 + h (h==7 pad)
    const int jrev = ((u & 1) << 4) | (((u >> 1) & 1) << 3) | (((u >> 2) & 1) << 2)
                   | (((u >> 3) & 1) << 1) | ((u >> 4) & 1);
    const float scale = 0.0883883476483184f;  // 128^-0.5
    #pragma unroll
    for (int bb = 0; bb < 2; ++bb) {
        float vals[32];
        #pragma unroll
        for (int kl = 0; kl < 4; ++kl) vals[kl * 8 + 7] = 0.f;   // pad head
        #pragma unroll
        for (int h = 0; h < H_; ++h) {
            const float4 qv = qL4[h * 32 + u];
            #pragma unroll
            for (int kl = 0; kl < 4; ++kl) {
                const float4 vv = v[bb * 4 + kl];
                float d = vv.x * qv.x;
                d = fmaf(vv.y, qv.y, d);
                d = fmaf(vv.z, qv.z, d);
                d = fmaf(vv.w, qv.w, d);
                vals[kl * 8 + h] = d;
            }
        }
        #pragma unroll
        for (int s = 0; s < 5; ++s) {
            const int m    = 1 << s;
            const int half = 16 >> s;          // 16,8,4,2,1
            const bool hi  = (u & m) != 0;
            #pragma unroll
            for (int i = 0; i < half; ++i) {
                const float mine = hi ? vals[i] : vals[i + half];
                const float keep = hi ? vals[i + half] : vals[i];
                vals[i] = keep + __shfl_xor(mine, m);
            }
        }
        const int kl = jrev >> 3;
        const int h  = jrev & 7;
        if (h < H_)
            LG[h * 68 + g * 8 + bb * 4 + kl] = vals[0] * scale;
    }
    __syncthreads();

    // ---- softmax over n (one wave per h, two rounds) ----
    {
        const int wv   = tid >> 6;
        const int lane = tid & 63;
        #pragma unroll
        for (int rep = 0; rep < 2; ++rep) {
            const int h = wv + rep * 4;
            if (h < H_) {
                const float x = LG[h * 68 + lane];
                float m = x;
                #pragma unroll
                for (int k = 32; k >= 1; k >>= 1)
                    m = fmaxf(m, __shfl_xor(m, k));
                const float e = __expf(x - m);
                float s = e;
                #pragma unroll
                for (int k = 32; k >= 1; k >>= 1)
                    s += __shfl_xor(s, k);
                WS[h * 68 + lane] = e / s;
            }
        }
    }
    __syncthreads();

    // ---- ctx from the retained registers ----
    {
        float4 acc[H_];
        #pragma unroll
        for (int h = 0; h < H_; ++h) { acc[h].x = acc[h].y = acc[h].z = acc[h].w = 0.f; }
        #pragma unroll
        for (int k = 0; k < 8; ++k) {
            const int row = g * 8 + k;
            #pragma unroll
            for (int h = 0; h < H_; ++h) {
                const float w = WS[h * 68 + row];   // broadcast within half-wave
                acc[h].x = fmaf(w, v[k].x, acc[h].x);
                acc[h].y = fmaf(w, v[k].y, acc[h].y);
                acc[h].z = fmaf(w, v[k].z, acc[h].z);
                acc[h].w = fmaf(w, v[k].w, acc[h].w);
            }
        }
        // fold the wave's two row-groups (lane u <-> u+32)
        #pragma unroll
        for (int h = 0; h < H_; ++h) {
            acc[h].x += __shfl_xor(acc[h].x, 32);
            acc[h].y += __shfl_xor(acc[h].y, 32);
            acc[h].z += __shfl_xor(acc[h].z, 32);
            acc[h].w += __shfl_xor(acc[h].w, 32);
        }
        const int wv = tid >> 6;
        if ((tid & 63) < 32) {
            #pragma unroll
            for (int h = 0; h < H_; ++h)
                P4[(wv * H_ + h) * 32 + u] = acc[h];
        }
    }
    __syncthreads();

    // ---- final 4-way reduce + coalesced store ----
    if (tid < H_ * 32) {
        const int h = tid >> 5;
        const int uu = tid & 31;
        float4 sum; sum.x = sum.y = sum.z = sum.w = 0.f;
        #pragma unroll
        for (int wv = 0; wv < 4; ++wv) {
            const float4 p = P4[(wv * H_ + h) * 32 + uu];
            sum.x += p.x; sum.y += p.y; sum.z += p.z; sum.w += p.w;
        }
        *reinterpret_cast<float4*>(out + ((size_t)bt * H_ + h) * D_ + uu * 4) = sum;
    }
}

extern "C" void kernel_launch(void* const* d_in, const int* in_sizes, int n_in,
                              void* d_out, int out_size, void* d_ws, size_t ws_size,
                              hipStream_t stream) {
    // d_in[0] = ego (B,T,D) -- unused by the reference computation
    const float* others  = (const float*)d_in[1];   // (B,N,T,D) f32
    const float* queries = (const float*)d_in[2];   // (H,D) f32
    float* out = (float*)d_out;                     // (B,T,H,D) f32

    dim3 grid(B_ * T_);
    dim3 block(256);
    MultiHeadPool_45226005627089_kernel<<<grid, block, 0, stream>>>(others, queries, out);
}